// Round 2
// baseline (617.531 us; speedup 1.0000x reference)
//
#include <hip/hip_runtime.h>

// x: (T=128, B=4, E=10000, F=16) fp32, dummy_index d = 0.
// out: (128, 4, 10000, 15) fp32 = tanh(cumsum_T(x[...,1:] * dt)),
// dt[0] = t[0]+t[1], dt[k] = t[k]-t[k-1], t = x[...,0].
//
// Mapping: 4 threads per (b,e) group; each thread owns one float4 of F.
// Chunked unroll over T (CH=8) keeps 8 independent dwordx4 loads in flight
// per thread (latency fix vs R1's prefetch-distance-1, which ran at 1.2 TB/s).

#define TT   128
#define CH   8                // T-chunk / prefetch depth
#define X4_T 160000           // per-t stride in float4 units (B*E*F/4)
#define O_T  600000           // per-t stride in floats (B*E*15)

__device__ __forceinline__ float fast_tanh(float x) {
  float e = __expf(2.0f * x);
  return 1.0f - __fdividef(2.0f, e + 1.0f);
}

__global__ __launch_bounds__(64) void integ_kernel(const float* __restrict__ x,
                                                   float* __restrict__ out) {
  const int gid  = blockIdx.x * 64 + threadIdx.x;    // 2500*64 = 160000 exactly
  const int idx  = gid >> 2;                          // (b,e) group, 0..39999
  const int sub  = gid & 3;                           // float4 slot within F=16
  const int lane = threadIdx.x & 63;
  const int srcl = lane & ~3;                         // group leader (dt channel)

  const float4* xv = reinterpret_cast<const float4*>(x) + ((size_t)idx * 4 + sub);
  float* ob = out + (size_t)idx * 15 + (4 * sub - 1); // j = 4*sub-1+c; sub0/c0 skipped

  float4 cur[CH], nxt[CH];
#pragma unroll
  for (int i = 0; i < CH; ++i) cur[i] = xv[(size_t)i * X4_T];

  float a0 = 0.f, a1 = 0.f, a2 = 0.f, a3 = 0.f;
  float tprev = 0.f;

  for (int tb = 0; tb < TT; tb += CH) {
    // Issue next chunk's 8 loads before consuming the current chunk.
    // Tail clamps to t=127 (redundant L2-hot reloads, harmless).
#pragma unroll
    for (int i = 0; i < CH; ++i) {
      int tn = tb + CH + i;
      if (tn > TT - 1) tn = TT - 1;
      nxt[i] = xv[(size_t)tn * X4_T];
    }

    float tc[CH];
#pragma unroll
    for (int i = 0; i < CH; ++i) tc[i] = __shfl(cur[i].x, srcl, 64);

#pragma unroll
    for (int i = 0; i < CH; ++i) {
      const int t = tb + i;
      const float dt = (t == 0) ? (tc[0] + tc[1]) : (tc[i] - tprev);
      a0 = fmaf(cur[i].x, dt, a0);
      a1 = fmaf(cur[i].y, dt, a1);
      a2 = fmaf(cur[i].z, dt, a2);
      a3 = fmaf(cur[i].w, dt, a3);

      float* o = ob + (size_t)t * O_T;
      if (sub) __builtin_nontemporal_store(fast_tanh(a0), o + 0);
      __builtin_nontemporal_store(fast_tanh(a1), o + 1);
      __builtin_nontemporal_store(fast_tanh(a2), o + 2);
      __builtin_nontemporal_store(fast_tanh(a3), o + 3);

      tprev = tc[i];
    }

#pragma unroll
    for (int i = 0; i < CH; ++i) cur[i] = nxt[i];
  }
}

extern "C" void kernel_launch(void* const* d_in, const int* in_sizes, int n_in,
                              void* d_out, int out_size, void* d_ws, size_t ws_size,
                              hipStream_t stream) {
  const float* x = (const float*)d_in[0];
  float* out = (float*)d_out;
  integ_kernel<<<dim3(2500), dim3(64), 0, stream>>>(x, out);
}

// Round 4
// 545.978 us; speedup vs baseline: 1.1311x; 1.1311x over previous
//
#include <hip/hip_runtime.h>

// x: (T=128, B=4, E=10000, F=16) fp32, d = 0.
// out: (128, 4, 10000, 15) fp32 = tanh(cumsum_T(x[...,1:] * dt)),
// dt[0] = t[0]+t[1], dt[k] = t[k]-t[k-1], t = x[...,0].
//
// R4 = R3 with the compile fix: __builtin_nontemporal_store needs a clang
// native vector type, not HIP's float4 class. Everything else unchanged:
// repack each timestep's 240 output floats (16 groups x 15) through a
// double-buffered LDS tile; lanes 0..59 store one aligned 16B vector each
// -> one fully-coalesced 960B store per wave per t (fixes R2's 1.59x
// WRITE_SIZE from partial-line scalar nt-stores).

#define TT   128
#define CH   8                 // T-chunk / prefetch depth
#define X4_T 160000            // per-t stride of x in float4 units (B*E*F/4)
#define O_T  600000            // per-t stride of out in floats (B*E*15)

typedef float vf4 __attribute__((ext_vector_type(4)));  // native vector for nt-store

__device__ __forceinline__ float fast_tanh(float x) {
  float e = __expf(2.0f * x);
  return 1.0f - __fdividef(2.0f, e + 1.0f);
}

__global__ __launch_bounds__(64) void integ_kernel(const float* __restrict__ x,
                                                   float* __restrict__ out) {
  __shared__ float buf[2][240];                     // 2 x 960 B, 16B-aligned halves

  const int lane = threadIdx.x;                     // 0..63
  const int grp  = lane >> 2;                       // 0..15 (local (b,e) group)
  const int sub  = lane & 3;                        // float4 slot within F=16
  const int srcl = lane & ~3;                       // group leader (dt channel)
  const int idx  = blockIdx.x * 16 + grp;           // global group, 0..39999

  const float4* xv = reinterpret_cast<const float4*>(x) + ((size_t)idx * 4 + sub);
  // LDS write base: word grp*15 + (4*sub - 1 + c); sub==0,c==0 is the dropped dt chan.
  const int wbase = grp * 15 + 4 * sub - 1;
  // Output base for this block's 60 16B-vectors per timestep.
  float* const oblk = out + (size_t)blockIdx.x * 240;

  float4 cur[CH], nxt[CH];
#pragma unroll
  for (int i = 0; i < CH; ++i) cur[i] = xv[(size_t)i * X4_T];

  float a0 = 0.f, a1 = 0.f, a2 = 0.f, a3 = 0.f;
  float tprev = 0.f;

  for (int tb = 0; tb < TT; tb += CH) {
    // Next chunk's 8 independent loads in flight while we consume cur.
#pragma unroll
    for (int i = 0; i < CH; ++i) {
      int tn = tb + CH + i;
      if (tn > TT - 1) tn = TT - 1;                 // tail: L2-hot redundant reload
      nxt[i] = xv[(size_t)tn * X4_T];
    }

    float tc[CH];
#pragma unroll
    for (int i = 0; i < CH; ++i) tc[i] = __shfl(cur[i].x, srcl, 64);

#pragma unroll
    for (int i = 0; i < CH; ++i) {
      const int t = tb + i;
      const float dt = (t == 0) ? (tc[0] + tc[1]) : (tc[i] - tprev);
      a0 = fmaf(cur[i].x, dt, a0);
      a1 = fmaf(cur[i].y, dt, a1);
      a2 = fmaf(cur[i].z, dt, a2);
      a3 = fmaf(cur[i].w, dt, a3);

      const int p = t & 1;
      float* w = &buf[p][wbase];
      if (sub) w[0] = fast_tanh(a0);
      w[1] = fast_tanh(a1);
      w[2] = fast_tanh(a2);
      w[3] = fast_tanh(a3);
      __syncthreads();                              // also covers WAR vs t+2 (same buf)
      if (lane < 60) {
        vf4 v4 = reinterpret_cast<const vf4*>(&buf[p][0])[lane];
        vf4* o4 = reinterpret_cast<vf4*>(oblk + (size_t)t * O_T);
        __builtin_nontemporal_store(v4, o4 + lane); // 960 B contiguous, full lines
      }
      tprev = tc[i];
    }

#pragma unroll
    for (int i = 0; i < CH; ++i) cur[i] = nxt[i];
  }
}

extern "C" void kernel_launch(void* const* d_in, const int* in_sizes, int n_in,
                              void* d_out, int out_size, void* d_ws, size_t ws_size,
                              hipStream_t stream) {
  const float* x = (const float*)d_in[0];
  float* out = (float*)d_out;
  integ_kernel<<<dim3(2500), dim3(64), 0, stream>>>(x, out);  // 2500*16 = 40000 groups
}